// Round 5
// baseline (319.353 us; speedup 1.0000x reference)
//
#include <hip/hip_runtime.h>
#include <hip/hip_bf16.h>
#include <cstdint>
#include <cstddef>

#define S_LEN   4096
#define BATCHN  4
#define DMODEL  1024
#define NHEADS  16
#define HDIM    64
#define MROWS   (S_LEN*BATCHN)   // 16384
#define NQKV    3072
#define KDIM    1024
#define KSPLIT  8
#define TP_PAD  66
#define BK      32
#define NT      (KDIM/BK)        // 32 K-tiles of 32

typedef __bf16 bf16;
typedef bf16 bf16x8 __attribute__((ext_vector_type(8)));
typedef bf16 bf16x4 __attribute__((ext_vector_type(4)));
typedef float f32x4 __attribute__((ext_vector_type(4)));
typedef float f32x16 __attribute__((ext_vector_type(16)));

#define MFMA_BF16_16(a,b,c) __builtin_amdgcn_mfma_f32_16x16x32_bf16(a,b,c,0,0,0)
#define MFMA_BF16_32(a,b,c) __builtin_amdgcn_mfma_f32_32x32x16_bf16(a,b,c,0,0,0)

__device__ __forceinline__ void gll16(const void* g, void* l) {
  __builtin_amdgcn_global_load_lds((const __attribute__((address_space(1))) unsigned*)g,
                                   (__attribute__((address_space(3))) unsigned*)l,
                                   16, 0, 0);
}

// ---------------- cast fp32 -> bf16, x4 vectorized ----------------
__global__ __launch_bounds__(256) void cast_bf16(const float* __restrict__ src,
                                                 bf16* __restrict__ dst, int n) {
  int stride = gridDim.x * blockDim.x * 4;
  for (int i = (blockIdx.x * blockDim.x + threadIdx.x) * 4; i < n; i += stride) {
    float4 f = *(const float4*)(src + i);
    bf16x4 o; o[0]=(bf16)f.x; o[1]=(bf16)f.y; o[2]=(bf16)f.z; o[3]=(bf16)f.w;
    *(bf16x4*)(dst + i) = o;
  }
}

// ---------------- 256x128 8-wave GEMM, BK=32, 32x32x16 MFMA, triple-buffer ----------------
// LDS per tile: A[256][32] 16KB + B[128][32] 8KB = 24KB; 3 buffers = 72KB -> 2 blocks/CU.
// Swizzle (both sides): stored element at byte row*64 + c16*16 is source column
// (c16*8) ^ (((row>>3)&1)<<4). Fragment read recovers col = ks*16 + (lane>>5)*8.
// Ledger: prologue stages t0,t1 (6), vmcnt(3) drains t0. Tile t stages t+2 (3 chunks),
// end-of-tile vmcnt(3) drains t+1 (t<NT-2); vmcnt(0) at t==NT-2; nothing at NT-1.
template<int MODE>
__global__ __launch_bounds__(512, 4) void gemm256(
    const bf16* __restrict__ Ah, const bf16* __restrict__ Ax,
    const bf16* __restrict__ Bw,
    const float* __restrict__ b0, const float* __restrict__ b1,
    const float* __restrict__ b2,
    void* __restrict__ Cout) {
  __shared__ __align__(16) char smem[3][24576];
  const int tid  = threadIdx.x;
  const int wid  = tid >> 6, lane = tid & 63;
  const int wm   = wid >> 1, wn = wid & 1;        // 4M x 2N waves, each owns 64x64
  const int NTL  = (MODE == 0) ? 24 : 8;
  const int nwg  = gridDim.x;
  const int bid  = blockIdx.x;
  const int wg   = (bid & 7) * (nwg >> 3) + (bid >> 3);   // bijective XCD swizzle (nwg%8==0)
  const int ntile = wg % NTL, mtile = wg / NTL;

  const bf16* Ap = (MODE == 0) ? ((ntile < 8) ? Ah : Ax) : Ah;
  const bf16* Abase = Ap + (size_t)mtile * 256 * KDIM;
  const bf16* Bbase = Bw + (size_t)ntile * 128 * KDIM;

  // staging slots: 3 chunks of 16B per thread per tile
  const bf16* sp[3]; int sd[3];
  #pragma unroll
  for (int j = 0; j < 3; ++j) {
    int o = j * 512 + tid;
    if (o < 1024) {           // A: 1024 chunks, 4 per row
      int row = o >> 2, c16 = o & 3, f = (row >> 3) & 1;
      sd[j] = row * 64 + c16 * 16;
      sp[j] = Abase + row * KDIM + ((c16 * 8) ^ (f << 4));
    } else {                  // B: 512 chunks
      int cb = o - 1024;
      int row = cb >> 2, c16 = cb & 3, f = (row >> 3) & 1;
      sd[j] = 16384 + row * 64 + c16 * 16;
      sp[j] = Bbase + row * KDIM + ((c16 * 8) ^ (f << 4));
    }
  }

  // fragment byte offsets (32x32 operand: row = lane&31, k-half = lane>>5)
  const int l31 = lane & 31, hi = lane >> 5, fl = (lane >> 3) & 1;
  int aOff[2][2], bOff[2][2];   // [ks][m/n]
  #pragma unroll
  for (int ks = 0; ks < 2; ++ks) {
    #pragma unroll
    for (int m = 0; m < 2; ++m)
      aOff[ks][m] = (wm * 64 + m * 32 + l31) * 64 + (((ks ^ fl) << 5) | (hi << 4));
    #pragma unroll
    for (int n = 0; n < 2; ++n)
      bOff[ks][n] = 16384 + (wn * 64 + n * 32 + l31) * 64 + (((ks ^ fl) << 5) | (hi << 4));
  }

  f32x16 acc[2][2] = {};

  // prologue: stage tiles 0 and 1
  #pragma unroll
  for (int j = 0; j < 3; ++j) gll16(sp[j],      smem[0] + sd[j]);
  #pragma unroll
  for (int j = 0; j < 3; ++j) gll16(sp[j] + BK, smem[1] + sd[j]);
  asm volatile("s_waitcnt vmcnt(3)" ::: "memory");
  __builtin_amdgcn_s_barrier();

  int cur = 0, nx2 = 2;
  for (int t = 0; t < NT; ++t) {
    const char* rb = smem[cur];
    char* wb = (char*)smem[nx2];

    bf16x8 aF[2][2], bF[2][2];
    #pragma unroll
    for (int ks = 0; ks < 2; ++ks) {
      #pragma unroll
      for (int m = 0; m < 2; ++m) aF[ks][m] = *(const bf16x8*)(rb + aOff[ks][m]);
      #pragma unroll
      for (int n = 0; n < 2; ++n) bF[ks][n] = *(const bf16x8*)(rb + bOff[ks][n]);
    }
    if (t + 2 < NT) {
      #pragma unroll
      for (int j = 0; j < 3; ++j) gll16(sp[j] + (t + 2) * BK, wb + sd[j]);
    }
    #pragma unroll
    for (int ks = 0; ks < 2; ++ks)
      #pragma unroll
      for (int m = 0; m < 2; ++m)
        #pragma unroll
        for (int n = 0; n < 2; ++n)
          acc[m][n] = MFMA_BF16_32(aF[ks][m], bF[ks][n], acc[m][n]);

    if (t < NT - 2)       asm volatile("s_waitcnt vmcnt(3)" ::: "memory");
    else if (t == NT - 2) asm volatile("s_waitcnt vmcnt(0)" ::: "memory");
    __builtin_amdgcn_s_barrier();
    cur = (cur == 2) ? 0 : cur + 1;
    nx2 = (nx2 == 2) ? 0 : nx2 + 1;
  }

  // epilogue: C layout 32x32: col=lane&31, row=(r&3)+8*(r>>2)+4*(lane>>5)
  #pragma unroll
  for (int m = 0; m < 2; ++m) {
    #pragma unroll
    for (int n = 0; n < 2; ++n) {
      const int col = ntile * 128 + wn * 64 + n * 32 + l31;
      if (MODE == 0) {
        const float bias = (col < 1024) ? b0[col] : (col < 2048) ? b1[col - 1024] : b2[col - 2048];
        bf16* C = (bf16*)Cout;
        #pragma unroll
        for (int r = 0; r < 16; ++r) {
          int row = mtile * 256 + wm * 64 + m * 32 + (r & 3) + 8 * (r >> 2) + 4 * hi;
          float v = acc[m][n][r] + bias;
          if (col < 2048) v = (v > 0.f) ? v + 1.f : __expf(v);   // elu(x)+1
          C[(size_t)row * NQKV + col] = (bf16)v;
        }
      } else {
        const float bias = b0[col];
        float* C = (float*)Cout;
        #pragma unroll
        for (int r = 0; r < 16; ++r) {
          int row = mtile * 256 + wm * 64 + m * 32 + (r & 3) + 8 * (r >> 2) + 4 * hi;
          C[(size_t)row * DMODEL + col] = acc[m][n][r] + bias;
        }
      }
    }
  }
}

// ---------------- transpose K,V halves of qkv into [bh][d][s]; Ksum partials ----------------
__global__ __launch_bounds__(256) void transpose_kv(const bf16* __restrict__ QKV,
                                                    bf16* __restrict__ Kt,
                                                    bf16* __restrict__ Vt,
                                                    float* __restrict__ Ksumg) {
  const int bh = blockIdx.x;
  const int sc0 = blockIdx.y * 128;
  const int b = bh >> 4, hh = bh & 15;
  const int tid = threadIdx.x;
  __shared__ bf16 Kl[128*TP_PAD];
  __shared__ bf16 Vl[128*TP_PAD];
  __shared__ float red[256];

  const int c = tid & 7;
  #pragma unroll
  for (int i = 0; i < 4; ++i) {
    int sr = (tid >> 3) + i * 32;
    size_t gaddr = ((size_t)(sc0 + sr) * BATCHN + b) * NQKV + 1024 + hh*64 + c*8;
    bf16x8 kv = *(const bf16x8*)(QKV + gaddr);
    bf16x8 vv = *(const bf16x8*)(QKV + gaddr + 1024);
    *(bf16x8*)(Kl + sr*TP_PAD + c*8) = kv;
    *(bf16x8*)(Vl + sr*TP_PAD + c*8) = vv;
  }
  __syncthreads();

  const int d = tid & 63;
  float ks = 0.f;
  #pragma unroll
  for (int i = 0; i < 4; ++i) {
    int sc = (tid >> 6) + i * 4;
    bf16x8 ko, vo;
    #pragma unroll
    for (int j = 0; j < 8; ++j) {
      bf16 kvv = Kl[(sc*8 + j)*TP_PAD + d];
      ko[j] = kvv;
      ks += (float)kvv;
      vo[j] = Vl[(sc*8 + j)*TP_PAD + d];
    }
    size_t obase = (size_t)bh * 64 * S_LEN + (size_t)d * S_LEN + sc0 + sc*8;
    *(bf16x8*)(Kt + obase) = ko;
    *(bf16x8*)(Vt + obase) = vo;
  }
  red[tid] = ks;
  __syncthreads();
  if (tid < 64) {
    float s = red[tid] + red[tid+64] + red[tid+128] + red[tid+192];
    atomicAdd(&Ksumg[bh*64 + tid], s);
  }
}

// ---------------- KV[bh][d][v] = sum_s Kt[bh][d][s] * Vt[bh][v][s], split-K ----------------
__global__ __launch_bounds__(256) void kv_gemm(const bf16* __restrict__ Kt,
                                               const bf16* __restrict__ Vt,
                                               float* __restrict__ KVg) {
  const int bh = blockIdx.x;
  const int k0base = blockIdx.y * (S_LEN / KSPLIT);
  const int tid = threadIdx.x, wid = tid >> 6, lane = tid & 63;
  const int wm = wid >> 1, wn = wid & 1;
  __shared__ __align__(16) bf16 Ks[64*64];
  __shared__ __align__(16) bf16 Vs[64*64];
  const bf16* Kh = Kt + (size_t)bh * 64 * S_LEN;
  const bf16* Vh = Vt + (size_t)bh * 64 * S_LEN;
  f32x4 acc[2][2] = {};

  for (int k0 = k0base; k0 < k0base + S_LEN/KSPLIT; k0 += 64) {
    #pragma unroll
    for (int j = 0; j < 4; ++j) {
      int cchunk = wid*4 + j;
      int r = (cchunk & 7) * 8 + (lane >> 3);
      int colb = (lane & 7) * 16;
      int scol = colb ^ ((r & 7) << 4);
      const bf16* src = (cchunk < 8) ? Kh : Vh;
      bf16* dst = ((cchunk < 8) ? Ks : Vs) + (size_t)(cchunk & 7) * 8 * 64;
      gll16(src + (size_t)r * S_LEN + k0 + (scol >> 1), dst);
    }
    __syncthreads();
    #pragma unroll
    for (int ksb = 0; ksb < 2; ++ksb) {
      bf16x8 af[2], bv[2];
      #pragma unroll
      for (int m = 0; m < 2; ++m) {
        int R = wm*32 + m*16 + (lane & 15);
        int cb = (ksb*64 + ((lane >> 4) << 4)) ^ ((R & 7) << 4);
        af[m] = *(const bf16x8*)((const char*)Ks + R*128 + cb);
      }
      #pragma unroll
      for (int n = 0; n < 2; ++n) {
        int R = wn*32 + n*16 + (lane & 15);
        int cb = (ksb*64 + ((lane >> 4) << 4)) ^ ((R & 7) << 4);
        bv[n] = *(const bf16x8*)((const char*)Vs + R*128 + cb);
      }
      #pragma unroll
      for (int m = 0; m < 2; ++m)
        #pragma unroll
        for (int n = 0; n < 2; ++n)
          acc[m][n] = MFMA_BF16_16(af[m], bv[n], acc[m][n]);
    }
    __syncthreads();
  }

  #pragma unroll
  for (int m = 0; m < 2; ++m)
    #pragma unroll
    for (int n = 0; n < 2; ++n)
      #pragma unroll
      for (int i = 0; i < 4; ++i) {
        int dd = wm*32 + m*16 + ((lane >> 4) << 2) + i;
        int vv = wn*32 + n*16 + (lane & 15);
        atomicAdd(&KVg[(size_t)bh*4096 + dd*64 + vv], acc[m][n][i]);
      }
}

// ---------------- out_pre = (Qp @ KV) / Z ----------------
__global__ __launch_bounds__(256) void attn_out(const bf16* __restrict__ QKV,
                                                const float* __restrict__ KVg,
                                                const float* __restrict__ Ksumg,
                                                bf16* __restrict__ OP) {
  const int head = blockIdx.x, stile = blockIdx.y;
  const int b = head >> 4, hh = head & 15;
  const int tid = threadIdx.x;
  const int wid = tid >> 6, lane = tid & 63;
  const int s0 = stile * 128;
  __shared__ __align__(16) bf16 Qs[128*64];
  __shared__ __align__(16) bf16 KVt[64*64];
  __shared__ float ksum_s[64];
  __shared__ float rZ[128];

  const float* KVh = KVg + (size_t)head*4096;
  #pragma unroll
  for (int i = 0; i < 16; ++i) {
    int idx = i*256 + tid;
    int dd = idx >> 6, vv = idx & 63;
    KVt[vv*64 + dd] = (bf16)KVh[idx];
  }
  if (tid < 64) ksum_s[tid] = Ksumg[head*64 + tid];
  #pragma unroll
  for (int p = 0; p < 4; ++p) {
    int row = p*32 + wid*8 + (lane >> 3);
    gll16(QKV + ((size_t)(s0+row)*BATCHN + b)*NQKV + hh*64 + ((lane&7)<<3),
          Qs + (p*32 + wid*8)*64);
  }
  __syncthreads();

  if (tid < 128) {
    float z = 0.f;
    #pragma unroll
    for (int dd = 0; dd < 64; ++dd) z += (float)Qs[tid*64 + dd] * ksum_s[dd];
    rZ[tid] = 1.f / (z + 1e-6f);
  }
  __syncthreads();

  f32x4 acc[2][4] = {};
  #pragma unroll
  for (int ksb = 0; ksb < 2; ++ksb) {
    bf16x8 af[2], bv[4];
    #pragma unroll
    for (int m = 0; m < 2; ++m)
      af[m] = *(const bf16x8*)(Qs + (wid*32 + m*16 + (lane & 15))*64 + ksb*32 + ((lane>>4)<<3));
    #pragma unroll
    for (int n = 0; n < 4; ++n)
      bv[n] = *(const bf16x8*)(KVt + (n*16 + (lane & 15))*64 + ksb*32 + ((lane>>4)<<3));
    #pragma unroll
    for (int m = 0; m < 2; ++m)
      #pragma unroll
      for (int n = 0; n < 4; ++n)
        acc[m][n] = MFMA_BF16_16(af[m], bv[n], acc[m][n]);
  }

  #pragma unroll
  for (int m = 0; m < 2; ++m)
    #pragma unroll
    for (int n = 0; n < 4; ++n)
      #pragma unroll
      for (int i = 0; i < 4; ++i) {
        int row = wid*32 + m*16 + ((lane >> 4) << 2) + i;
        int vv  = n*16 + (lane & 15);
        float val = acc[m][n][i] * rZ[row];
        OP[((size_t)(s0+row)*BATCHN + b)*DMODEL + hh*64 + vv] = (bf16)val;
      }
}

// ---------------- launch ----------------
extern "C" void kernel_launch(void* const* d_in, const int* in_sizes, int n_in,
                              void* d_out, int out_size, void* d_ws, size_t ws_size,
                              hipStream_t stream) {
  const float* h  = (const float*)d_in[0];
  const float* x  = (const float*)d_in[1];
  const float* Wq = (const float*)d_in[2];
  const float* bq = (const float*)d_in[3];
  const float* Wk = (const float*)d_in[4];
  const float* bk = (const float*)d_in[5];
  const float* Wv = (const float*)d_in[6];
  const float* bv = (const float*)d_in[7];
  const float* Wo = (const float*)d_in[8];
  const float* bo = (const float*)d_in[9];

  char* ws = (char*)d_ws;
  bf16*  hbf  = (bf16*)(ws);                    // 33,554,432 B  (reused as Kt)
  bf16*  xbf  = (bf16*)(ws + 33554432);         // 33,554,432 B  (reused as Vt)
  bf16*  wcat = (bf16*)(ws + 67108864);         //  6,291,456 B  [3072][1024]
  bf16*  wob  = (bf16*)(ws + 73400320);         //  2,097,152 B  [1024][1024]
  bf16*  qkv  = (bf16*)(ws + 75497472);         // 100,663,296 B [16384][3072]
  float* kvb  = (float*)(ws + 176160768);       //  1,048,576 B  [64][64][64]
  float* ksb  = (float*)(ws + 177209344);       //     16,384 B  [64][64]
  bf16*  op   = (bf16*)(ws + 177225728);        // 33,554,432 B  [16384][1024]

  bf16* Kt = hbf;
  bf16* Vt = xbf;

  cast_bf16<<<dim3(2048), 256, 0, stream>>>(h, hbf, MROWS*KDIM);
  cast_bf16<<<dim3(2048), 256, 0, stream>>>(x, xbf, MROWS*KDIM);
  cast_bf16<<<dim3(512),  256, 0, stream>>>(Wq, wcat,           1048576);
  cast_bf16<<<dim3(512),  256, 0, stream>>>(Wk, wcat + 1048576, 1048576);
  cast_bf16<<<dim3(512),  256, 0, stream>>>(Wv, wcat + 2097152, 1048576);
  cast_bf16<<<dim3(512),  256, 0, stream>>>(Wo, wob,            1048576);

  hipMemsetAsync(kvb, 0, 1048576 + 16384, stream);

  gemm256<0><<<dim3(1536), 512, 0, stream>>>(hbf, xbf, wcat, bq, bk, bv, qkv);
  transpose_kv<<<dim3(64, 32), 256, 0, stream>>>(qkv, Kt, Vt, ksb);
  kv_gemm<<<dim3(64, KSPLIT), 256, 0, stream>>>(Kt, Vt, kvb);
  attn_out<<<dim3(64, 32), 256, 0, stream>>>(qkv, kvb, ksb, op);
  gemm256<1><<<dim3(512), 512, 0, stream>>>(op, nullptr, wob, bo, nullptr, nullptr, d_out);
}